// Round 6
// baseline (214.252 us; speedup 1.0000x reference)
//
#include <hip/hip_runtime.h>
#include <hip/hip_bf16.h>
#include <stdint.h>

#define B_DIM 8192
#define D_DIM 2048
#define U_DIM 2048
#define KWORDS 64            // bit path: 2048 bits = 64 u32 words

typedef int v4i  __attribute__((ext_vector_type(4)));
typedef int v16i __attribute__((ext_vector_type(16)));

// ======================= i8 MFMA PATH =======================

// x [B][D] f32 -> xi [B][D] i8 (+1/-1). float4 in, packed u32 out. Coalesced.
__global__ void pack_x_i8(const float* __restrict__ x, char* __restrict__ xi) {
    int idx = blockIdx.x * 256 + threadIdx.x;
    float4 v = ((const float4*)x)[idx];
    unsigned b0 = (v.x >= 0.f) ? 0x01u : 0xFFu;
    unsigned b1 = (v.y >= 0.f) ? 0x01u : 0xFFu;
    unsigned b2 = (v.z >= 0.f) ? 0x01u : 0xFFu;
    unsigned b3 = (v.w >= 0.f) ? 0x01u : 0xFFu;
    ((unsigned*)xi)[idx] = b0 | (b1 << 8) | (b2 << 16) | (b3 << 24);
}

// k [D][U] f32 -> kt [U][D] i8 (+1/-1), transposed via LDS 64x64 tile.
__global__ void pack_kt_i8(const float* __restrict__ k, char* __restrict__ kt) {
    __shared__ float tile[64][65];
    const int j0 = (blockIdx.x & 31) * 64;   // U tile
    const int d0 = (blockIdx.x >> 5) * 64;   // D tile
    const int tid = threadIdx.x;
    const int lane = tid & 63;
    const int wv = tid >> 6;
    for (int i = 0; i < 16; i++) {
        int row = i * 4 + wv;
        tile[row][lane] = k[(size_t)(d0 + row) * U_DIM + j0 + lane];
    }
    __syncthreads();
    const int u = tid >> 2;          // 0..63 output row (unit)
    const int g = tid & 3;           // 16-byte group along D
    union { char c[16]; int4 v; } pk;
#pragma unroll
    for (int j = 0; j < 16; j++)
        pk.c[j] = (tile[g * 16 + j][u] >= 0.f) ? (char)1 : (char)-1;
    *(int4*)(kt + (size_t)(j0 + u) * D_DIM + d0 + g * 16) = pk.v;
}

// out[i][j] = sum_k xi[i][k]*kt[j][k] + bias[j], exact in i32.
// 128x128 tile, 256 thr = 4 waves, wave = 64x64 (2x2 MFMA tiles of 32x32).
// B chunk (128 rows x 128 K-bytes = 16KB) in LDS, 16B groups XOR-swizzled by
// row (g ^ (r&7)) via global-address permute -> frag reads have exactly 8
// distinct addrs per 4-bank group = b128 baseline, zero extra conflicts.
// A read direct from global (16B/lane, L2-resident after first col-tile pass).
__launch_bounds__(256)
__global__ void gemm_i8(const char* __restrict__ xi,   // [8192][2048]
                        const char* __restrict__ kt,   // [2048][2048]
                        const float* __restrict__ bias,
                        float* __restrict__ out) {
    __shared__ char bsm[128 * 128];  // 16KB
    const int tid  = threadIdx.x;
    const int lane = tid & 63;
    const int w    = tid >> 6;       // 4 waves
    const int rows0 = blockIdx.y * 128;
    const int cols0 = blockIdx.x * 128;
    const int wr = (w >> 1) * 64;    // wave row offset
    const int wc = (w & 1) * 64;     // wave col offset
    const int m    = lane & 31;
    const int half = lane >> 5;

    v16i acc[2][2];
#pragma unroll
    for (int rt = 0; rt < 2; rt++)
#pragma unroll
        for (int ct = 0; ct < 2; ct++)
#pragma unroll
            for (int i = 0; i < 16; i++) acc[rt][ct][i] = 0;

    const size_t arow0 = (size_t)(rows0 + wr + m) * D_DIM;
    const size_t arow1 = arow0 + (size_t)32 * D_DIM;

    for (int ch = 0; ch < 16; ch++) {
        if (ch) __syncthreads();
        // stage B chunk: slot (r,g) <- global group g^(r&7) of row cols0+r
#pragma unroll
        for (int i = 0; i < 4; i++) {
            int flat = i * 256 + tid;          // 0..1023
            int r  = flat >> 3;                // 0..127
            int g  = flat & 7;
            int gg = g ^ (r & 7);
            int4 v = *(const int4*)(kt + (size_t)(cols0 + r) * D_DIM + ch * 128 + gg * 16);
            *(int4*)&bsm[r * 128 + g * 16] = v;
        }
        __syncthreads();

#pragma unroll
        for (int kk = 0; kk < 4; kk++) {
            const int koff = ch * 128 + kk * 32 + half * 16;
            v4i a0 = *(const v4i*)(xi + arow0 + koff);
            v4i a1 = *(const v4i*)(xi + arow1 + koff);
            const int lg = kk * 2 + half;
            const int sw = (lg ^ (m & 7)) << 4;
            v4i b0 = *(const v4i*)&bsm[(wc + m) * 128 + sw];
            v4i b1 = *(const v4i*)&bsm[(wc + 32 + m) * 128 + sw];
            acc[0][0] = __builtin_amdgcn_mfma_i32_32x32x32_i8(a0, b0, acc[0][0], 0, 0, 0);
            acc[0][1] = __builtin_amdgcn_mfma_i32_32x32x32_i8(a0, b1, acc[0][1], 0, 0, 0);
            acc[1][0] = __builtin_amdgcn_mfma_i32_32x32x32_i8(a1, b0, acc[1][0], 0, 0, 0);
            acc[1][1] = __builtin_amdgcn_mfma_i32_32x32x32_i8(a1, b1, acc[1][1], 0, 0, 0);
        }
    }

    // C/D 32x32 layout (HW-verified): col = lane&31, row = (reg&3)+8*(reg>>2)+4*half
#pragma unroll
    for (int rt = 0; rt < 2; rt++)
#pragma unroll
        for (int ct = 0; ct < 2; ct++) {
            const int n = cols0 + wc + ct * 32 + m;
            const float bb = bias[n];
#pragma unroll
            for (int reg = 0; reg < 16; reg++) {
                const int row = (reg & 3) + 8 * (reg >> 2) + 4 * half;
                const size_t grow = (size_t)(rows0 + wr + rt * 32 + row);
                out[grow * U_DIM + n] = (float)acc[rt][ct][reg] + bb;
            }
        }
}

// ======================= BIT-PATH FALLBACK (R5, proven) =======================

__global__ void pack_x_kernel(const float* __restrict__ x,
                              unsigned long long* __restrict__ xb) {
    const int gwave = (blockIdx.x * blockDim.x + threadIdx.x) >> 6;
    const int lane  = threadIdx.x & 63;
    const size_t base = (size_t)gwave * 256;
    float v0 = x[base + lane];
    float v1 = x[base + 64 + lane];
    float v2 = x[base + 128 + lane];
    float v3 = x[base + 192 + lane];
    unsigned long long m0 = __ballot(v0 >= 0.0f);
    unsigned long long m1 = __ballot(v1 >= 0.0f);
    unsigned long long m2 = __ballot(v2 >= 0.0f);
    unsigned long long m3 = __ballot(v3 >= 0.0f);
    if (lane == 0) {
        ulonglong2* p = (ulonglong2*)(xb + (base >> 6));
        ulonglong2 a; a.x = m0; a.y = m1;
        ulonglong2 b; b.x = m2; b.y = m3;
        p[0] = a;
        p[1] = b;
    }
}

__global__ void pack_k_kernel(const float* __restrict__ k,
                              unsigned long long* __restrict__ kb) {
    __shared__ float tile[64][65];
    const int j0 = (blockIdx.x & 31) * 64;
    const int d0 = (blockIdx.x >> 5) * 64;
    const int tid  = threadIdx.x;
    const int lane = tid & 63;
    const int wv   = tid >> 6;
    for (int i = 0; i < 16; i++) {
        int row = i * 4 + wv;
        tile[row][lane] = k[(size_t)(d0 + row) * U_DIM + j0 + lane];
    }
    __syncthreads();
    for (int c = wv * 16; c < wv * 16 + 16; c++) {
        float v = tile[lane][c];
        unsigned long long m = __ballot(v >= 0.0f);
        if (lane == 0) kb[(size_t)(j0 + c) * (D_DIM / 64) + (d0 >> 6)] = m;
    }
}

__launch_bounds__(512)
__global__ void bgemm_kernel(const unsigned int* __restrict__ xb,
                             const unsigned int* __restrict__ kb,
                             const float* __restrict__ bias,
                             float* __restrict__ out) {
    __shared__ unsigned int xs[128 * KWORDS];
    __shared__ unsigned int ks[128 * KWORDS];
    const int bx  = blockIdx.x;
    const int by  = blockIdx.y;
    const int tid = threadIdx.x;
    const uint4* xsrc = (const uint4*)(xb + (size_t)(by * 128) * KWORDS);
    const uint4* ksrc = (const uint4*)(kb + (size_t)(bx * 128) * KWORDS);
#pragma unroll
    for (int i = 0; i < 4; i++) {
        int flat = tid + i * 512;
        int r    = flat >> 4;
        int g    = flat & 15;
        int sg   = g ^ ((r >> 3) & 7);
        uint4 xv = xsrc[flat];
        uint4 kv = ksrc[flat];
        *((uint4*)&xs[r * KWORDS + sg * 4]) = xv;
        *((uint4*)&ks[r * KWORDS + sg * 4]) = kv;
    }
    __syncthreads();
    const int tr   = (tid >> 4) * 4;
    const int tc   = (tid & 15) * 8;
    const int xswz = ((tid >> 4) >> 1) & 7;
    const int ksw  = tid & 7;
    int acc[4][8] = {};
    for (int w4 = 0; w4 < 16; w4++) {
        const int xcol = (w4 ^ xswz) * 4;
        const int kcol = (w4 ^ ksw) * 4;
        uint4 xv[4], kv[8];
#pragma unroll
        for (int r = 0; r < 4; r++) xv[r] = *((const uint4*)&xs[(tr + r) * KWORDS + xcol]);
#pragma unroll
        for (int c = 0; c < 8; c++) kv[c] = *((const uint4*)&ks[(tc + c) * KWORDS + kcol]);
#pragma unroll
        for (int r = 0; r < 4; r++)
#pragma unroll
            for (int c = 0; c < 8; c++) {
                acc[r][c] += __popc(xv[r].x ^ kv[c].x);
                acc[r][c] += __popc(xv[r].y ^ kv[c].y);
                acc[r][c] += __popc(xv[r].z ^ kv[c].z);
                acc[r][c] += __popc(xv[r].w ^ kv[c].w);
            }
    }
    const int row0 = by * 128 + tr;
    const int col0 = bx * 128 + tc;
    const float4 b0 = *((const float4*)&bias[col0]);
    const float4 b1 = *((const float4*)&bias[col0 + 4]);
#pragma unroll
    for (int r = 0; r < 4; r++) {
        float4 o0, o1;
        o0.x = (float)(D_DIM - 2 * acc[r][0]) + b0.x;
        o0.y = (float)(D_DIM - 2 * acc[r][1]) + b0.y;
        o0.z = (float)(D_DIM - 2 * acc[r][2]) + b0.z;
        o0.w = (float)(D_DIM - 2 * acc[r][3]) + b0.w;
        o1.x = (float)(D_DIM - 2 * acc[r][4]) + b1.x;
        o1.y = (float)(D_DIM - 2 * acc[r][5]) + b1.y;
        o1.z = (float)(D_DIM - 2 * acc[r][6]) + b1.z;
        o1.w = (float)(D_DIM - 2 * acc[r][7]) + b1.w;
        float* orow = &out[(size_t)(row0 + r) * U_DIM + col0];
        *((float4*)orow)       = o0;
        *((float4*)(orow + 4)) = o1;
    }
}

// ======================= launcher =======================

extern "C" void kernel_launch(void* const* d_in, const int* in_sizes, int n_in,
                              void* d_out, int out_size, void* d_ws, size_t ws_size,
                              hipStream_t stream) {
    const float* x    = (const float*)d_in[0];   // [8192][2048]
    const float* k    = (const float*)d_in[1];   // [2048][2048]
    const float* bias = (const float*)d_in[2];   // [2048]
    float* out = (float*)d_out;

    const size_t need_i8 = (size_t)B_DIM * D_DIM + (size_t)U_DIM * D_DIM; // ~21 MB
    if (ws_size >= need_i8) {
        char* xi = (char*)d_ws;                          // 16 MB
        char* kt = xi + (size_t)B_DIM * D_DIM;           // 4 MB
        pack_x_i8<<<(B_DIM * D_DIM) / 1024, 256, 0, stream>>>(x, xi);
        pack_kt_i8<<<32 * 32, 256, 0, stream>>>(k, kt);
        dim3 grid(U_DIM / 128, B_DIM / 128);
        gemm_i8<<<grid, 256, 0, stream>>>(xi, kt, bias, out);
    } else {
        unsigned long long* xbits = (unsigned long long*)d_ws;
        unsigned long long* kbits = (unsigned long long*)((char*)d_ws + (size_t)B_DIM * (D_DIM / 8));
        pack_x_kernel<<<(B_DIM * D_DIM) / 1024, 256, 0, stream>>>(x, xbits);
        pack_k_kernel<<<32 * 32, 256, 0, stream>>>(k, kbits);
        dim3 grid(U_DIM / 128, B_DIM / 128);
        bgemm_kernel<<<grid, 512, 0, stream>>>((const unsigned int*)xbits,
                                               (const unsigned int*)kbits, bias, out);
    }
}

// Round 7
// 171.347 us; speedup vs baseline: 1.2504x; 1.2504x over previous
//
#include <hip/hip_runtime.h>
#include <hip/hip_bf16.h>
#include <stdint.h>

#define B_DIM 8192
#define D_DIM 2048
#define U_DIM 2048
#define KWORDS 64            // bit path: 2048 bits = 64 u32 words

typedef int v4i  __attribute__((ext_vector_type(4)));
typedef int v16i __attribute__((ext_vector_type(16)));

// Async global->LDS DMA, 16B per lane. LDS dest is wave-uniform base + lane*16;
// global src may be per-lane arbitrary (we fold the bank swizzle there).
__device__ __forceinline__ void load_lds16(const char* g, char* l) {
    __builtin_amdgcn_global_load_lds(
        (const __attribute__((address_space(1))) unsigned int*)g,
        (__attribute__((address_space(3))) unsigned int*)l,
        16, 0, 0);
}

// ======================= i8 MFMA PATH =======================

// x [B][D] f32 -> xi [B][D] i8 (+1/-1). float4 in, packed u32 out. Coalesced.
__global__ void pack_x_i8(const float* __restrict__ x, char* __restrict__ xi) {
    int idx = blockIdx.x * 256 + threadIdx.x;
    float4 v = ((const float4*)x)[idx];
    unsigned b0 = (v.x >= 0.f) ? 0x01u : 0xFFu;
    unsigned b1 = (v.y >= 0.f) ? 0x01u : 0xFFu;
    unsigned b2 = (v.z >= 0.f) ? 0x01u : 0xFFu;
    unsigned b3 = (v.w >= 0.f) ? 0x01u : 0xFFu;
    ((unsigned*)xi)[idx] = b0 | (b1 << 8) | (b2 << 16) | (b3 << 24);
}

// k [D][U] f32 -> kt [U][D] i8 (+1/-1), transposed via LDS 64x64 tile.
__global__ void pack_kt_i8(const float* __restrict__ k, char* __restrict__ kt) {
    __shared__ float tile[64][65];
    const int j0 = (blockIdx.x & 31) * 64;   // U tile
    const int d0 = (blockIdx.x >> 5) * 64;   // D tile
    const int tid = threadIdx.x;
    const int lane = tid & 63;
    const int wv = tid >> 6;
    for (int i = 0; i < 16; i++) {
        int row = i * 4 + wv;
        tile[row][lane] = k[(size_t)(d0 + row) * U_DIM + j0 + lane];
    }
    __syncthreads();
    const int u = tid >> 2;          // 0..63 output row (unit)
    const int g = tid & 3;           // 16-byte group along D
    union { char c[16]; int4 v; } pk;
#pragma unroll
    for (int j = 0; j < 16; j++)
        pk.c[j] = (tile[g * 16 + j][u] >= 0.f) ? (char)1 : (char)-1;
    *(int4*)(kt + (size_t)(j0 + u) * D_DIM + d0 + g * 16) = pk.v;
}

// out[i][j] = sum_k xi[i][k]*kt[j][k] + bias[j], exact in i32.
// 128x128 tile, 256 thr = 4 waves, wave = 64x64 (2x2 of mfma_i32_32x32x32_i8).
// Per 128B K-chunk: A(16KB) + B(16KB) staged via async global_load_lds;
// bank swizzle folded into the GLOBAL source address (slot (r,g) holds global
// group g^(r&7)) -> frag reads conflict-free, staging stays coalesced
// (permutation within a 128B segment = same cache lines).
__launch_bounds__(256)
__global__ void gemm_i8(const char* __restrict__ xi,   // [8192][2048]
                        const char* __restrict__ kt,   // [2048][2048]
                        const float* __restrict__ bias,
                        float* __restrict__ out) {
    __shared__ uint4 asm4[1024];     // A chunk: 128 rows x 128 B
    __shared__ uint4 bsm4[1024];     // B chunk: 128 rows x 128 B
    char* asmem = (char*)asm4;
    char* bsmem = (char*)bsm4;

    const int tid  = threadIdx.x;
    const int lane = tid & 63;
    const int w    = tid >> 6;       // 4 waves
    const int rows0 = blockIdx.y * 128;
    const int cols0 = blockIdx.x * 128;
    const int wr = (w >> 1) * 64;    // wave row offset
    const int wc = (w & 1) * 64;     // wave col offset
    const int m    = lane & 31;
    const int half = lane >> 5;

    v16i acc[2][2];
#pragma unroll
    for (int rt = 0; rt < 2; rt++)
#pragma unroll
        for (int ct = 0; ct < 2; ct++)
#pragma unroll
            for (int i = 0; i < 16; i++) acc[rt][ct][i] = 0;

    const char* abase = xi + (size_t)rows0 * D_DIM;
    const char* bbase = kt + (size_t)cols0 * D_DIM;

    for (int ch = 0; ch < 16; ch++) {
        if (ch) __syncthreads();     // previous chunk fully consumed
        // Stage: wave w covers slots [w*256, w*256+256) of each array in 4
        // calls of 64 slots. slot -> (r = slot>>3, g = slot&7); global group
        // gg = g ^ (r&7).
#pragma unroll
        for (int i = 0; i < 4; i++) {
            const int slotbase = w * 256 + i * 64;
            const int slot = slotbase + lane;
            const int r  = slot >> 3;
            const int gg = (slot & 7) ^ (r & 7);
            const size_t goff = (size_t)r * D_DIM + ch * 128 + gg * 16;
            load_lds16(abase + goff, asmem + slotbase * 16);
            load_lds16(bbase + goff, bsmem + slotbase * 16);
        }
        __syncthreads();             // drains the DMA queue

#pragma unroll
        for (int kk = 0; kk < 4; kk++) {
            const int col = ((kk * 2 + half) ^ (m & 7)) << 4;
            v4i a0 = *(const v4i*)(asmem + (wr + m)      * 128 + col);
            v4i a1 = *(const v4i*)(asmem + (wr + 32 + m) * 128 + col);
            v4i b0 = *(const v4i*)(bsmem + (wc + m)      * 128 + col);
            v4i b1 = *(const v4i*)(bsmem + (wc + 32 + m) * 128 + col);
            acc[0][0] = __builtin_amdgcn_mfma_i32_32x32x32_i8(a0, b0, acc[0][0], 0, 0, 0);
            acc[0][1] = __builtin_amdgcn_mfma_i32_32x32x32_i8(a0, b1, acc[0][1], 0, 0, 0);
            acc[1][0] = __builtin_amdgcn_mfma_i32_32x32x32_i8(a1, b0, acc[1][0], 0, 0, 0);
            acc[1][1] = __builtin_amdgcn_mfma_i32_32x32x32_i8(a1, b1, acc[1][1], 0, 0, 0);
        }
    }

    // C/D 32x32 layout (HW-verified R6): col = lane&31, row = (reg&3)+8*(reg>>2)+4*half
#pragma unroll
    for (int rt = 0; rt < 2; rt++)
#pragma unroll
        for (int ct = 0; ct < 2; ct++) {
            const int n = cols0 + wc + ct * 32 + m;
            const float bb = bias[n];
#pragma unroll
            for (int reg = 0; reg < 16; reg++) {
                const int row = (reg & 3) + 8 * (reg >> 2) + 4 * half;
                const size_t grow = (size_t)(rows0 + wr + rt * 32 + row);
                out[grow * U_DIM + n] = (float)acc[rt][ct][reg] + bb;
            }
        }
}

// ======================= BIT-PATH FALLBACK (R5, proven) =======================

__global__ void pack_x_kernel(const float* __restrict__ x,
                              unsigned long long* __restrict__ xb) {
    const int gwave = (blockIdx.x * blockDim.x + threadIdx.x) >> 6;
    const int lane  = threadIdx.x & 63;
    const size_t base = (size_t)gwave * 256;
    float v0 = x[base + lane];
    float v1 = x[base + 64 + lane];
    float v2 = x[base + 128 + lane];
    float v3 = x[base + 192 + lane];
    unsigned long long m0 = __ballot(v0 >= 0.0f);
    unsigned long long m1 = __ballot(v1 >= 0.0f);
    unsigned long long m2 = __ballot(v2 >= 0.0f);
    unsigned long long m3 = __ballot(v3 >= 0.0f);
    if (lane == 0) {
        ulonglong2* p = (ulonglong2*)(xb + (base >> 6));
        ulonglong2 a; a.x = m0; a.y = m1;
        ulonglong2 b; b.x = m2; b.y = m3;
        p[0] = a;
        p[1] = b;
    }
}

__global__ void pack_k_kernel(const float* __restrict__ k,
                              unsigned long long* __restrict__ kb) {
    __shared__ float tile[64][65];
    const int j0 = (blockIdx.x & 31) * 64;
    const int d0 = (blockIdx.x >> 5) * 64;
    const int tid  = threadIdx.x;
    const int lane = tid & 63;
    const int wv   = tid >> 6;
    for (int i = 0; i < 16; i++) {
        int row = i * 4 + wv;
        tile[row][lane] = k[(size_t)(d0 + row) * U_DIM + j0 + lane];
    }
    __syncthreads();
    for (int c = wv * 16; c < wv * 16 + 16; c++) {
        float v = tile[lane][c];
        unsigned long long m = __ballot(v >= 0.0f);
        if (lane == 0) kb[(size_t)(j0 + c) * (D_DIM / 64) + (d0 >> 6)] = m;
    }
}

__launch_bounds__(512)
__global__ void bgemm_kernel(const unsigned int* __restrict__ xb,
                             const unsigned int* __restrict__ kb,
                             const float* __restrict__ bias,
                             float* __restrict__ out) {
    __shared__ unsigned int xs[128 * KWORDS];
    __shared__ unsigned int ks[128 * KWORDS];
    const int bx  = blockIdx.x;
    const int by  = blockIdx.y;
    const int tid = threadIdx.x;
    const uint4* xsrc = (const uint4*)(xb + (size_t)(by * 128) * KWORDS);
    const uint4* ksrc = (const uint4*)(kb + (size_t)(bx * 128) * KWORDS);
#pragma unroll
    for (int i = 0; i < 4; i++) {
        int flat = tid + i * 512;
        int r    = flat >> 4;
        int g    = flat & 15;
        int sg   = g ^ ((r >> 3) & 7);
        uint4 xv = xsrc[flat];
        uint4 kv = ksrc[flat];
        *((uint4*)&xs[r * KWORDS + sg * 4]) = xv;
        *((uint4*)&ks[r * KWORDS + sg * 4]) = kv;
    }
    __syncthreads();
    const int tr   = (tid >> 4) * 4;
    const int tc   = (tid & 15) * 8;
    const int xswz = ((tid >> 4) >> 1) & 7;
    const int ksw  = tid & 7;
    int acc[4][8] = {};
    for (int w4 = 0; w4 < 16; w4++) {
        const int xcol = (w4 ^ xswz) * 4;
        const int kcol = (w4 ^ ksw) * 4;
        uint4 xv[4], kv[8];
#pragma unroll
        for (int r = 0; r < 4; r++) xv[r] = *((const uint4*)&xs[(tr + r) * KWORDS + xcol]);
#pragma unroll
        for (int c = 0; c < 8; c++) kv[c] = *((const uint4*)&ks[(tc + c) * KWORDS + kcol]);
#pragma unroll
        for (int r = 0; r < 4; r++)
#pragma unroll
            for (int c = 0; c < 8; c++) {
                acc[r][c] += __popc(xv[r].x ^ kv[c].x);
                acc[r][c] += __popc(xv[r].y ^ kv[c].y);
                acc[r][c] += __popc(xv[r].z ^ kv[c].z);
                acc[r][c] += __popc(xv[r].w ^ kv[c].w);
            }
    }
    const int row0 = by * 128 + tr;
    const int col0 = bx * 128 + tc;
    const float4 b0 = *((const float4*)&bias[col0]);
    const float4 b1 = *((const float4*)&bias[col0 + 4]);
#pragma unroll
    for (int r = 0; r < 4; r++) {
        float4 o0, o1;
        o0.x = (float)(D_DIM - 2 * acc[r][0]) + b0.x;
        o0.y = (float)(D_DIM - 2 * acc[r][1]) + b0.y;
        o0.z = (float)(D_DIM - 2 * acc[r][2]) + b0.z;
        o0.w = (float)(D_DIM - 2 * acc[r][3]) + b0.w;
        o1.x = (float)(D_DIM - 2 * acc[r][4]) + b1.x;
        o1.y = (float)(D_DIM - 2 * acc[r][5]) + b1.y;
        o1.z = (float)(D_DIM - 2 * acc[r][6]) + b1.z;
        o1.w = (float)(D_DIM - 2 * acc[r][7]) + b1.w;
        float* orow = &out[(size_t)(row0 + r) * U_DIM + col0];
        *((float4*)orow)       = o0;
        *((float4*)(orow + 4)) = o1;
    }
}

// ======================= launcher =======================

extern "C" void kernel_launch(void* const* d_in, const int* in_sizes, int n_in,
                              void* d_out, int out_size, void* d_ws, size_t ws_size,
                              hipStream_t stream) {
    const float* x    = (const float*)d_in[0];   // [8192][2048]
    const float* k    = (const float*)d_in[1];   // [2048][2048]
    const float* bias = (const float*)d_in[2];   // [2048]
    float* out = (float*)d_out;

    const size_t need_i8 = (size_t)B_DIM * D_DIM + (size_t)U_DIM * D_DIM; // ~21 MB
    if (ws_size >= need_i8) {
        char* xi = (char*)d_ws;                          // 16 MB
        char* kt = xi + (size_t)B_DIM * D_DIM;           // 4 MB
        pack_x_i8<<<(B_DIM * D_DIM) / 1024, 256, 0, stream>>>(x, xi);
        pack_kt_i8<<<32 * 32, 256, 0, stream>>>(k, kt);
        dim3 grid(U_DIM / 128, B_DIM / 128);
        gemm_i8<<<grid, 256, 0, stream>>>(xi, kt, bias, out);
    } else {
        unsigned long long* xbits = (unsigned long long*)d_ws;
        unsigned long long* kbits = (unsigned long long*)((char*)d_ws + (size_t)B_DIM * (D_DIM / 8));
        pack_x_kernel<<<(B_DIM * D_DIM) / 1024, 256, 0, stream>>>(x, xbits);
        pack_k_kernel<<<32 * 32, 256, 0, stream>>>(k, kbits);
        dim3 grid(U_DIM / 128, B_DIM / 128);
        bgemm_kernel<<<grid, 512, 0, stream>>>((const unsigned int*)xbits,
                                               (const unsigned int*)kbits, bias, out);
    }
}

// Round 8
// 166.530 us; speedup vs baseline: 1.2866x; 1.0289x over previous
//
#include <hip/hip_runtime.h>
#include <hip/hip_bf16.h>
#include <stdint.h>

#define B_DIM 8192
#define D_DIM 2048
#define U_DIM 2048
#define KWORDS 64            // bit path: 2048 bits = 64 u32 words

typedef int v4i  __attribute__((ext_vector_type(4)));
typedef int v16i __attribute__((ext_vector_type(16)));

// Async global->LDS DMA, 16B per lane. LDS dest is wave-uniform base + lane*16;
// global src may be per-lane arbitrary (we fold the bank swizzle there).
__device__ __forceinline__ void load_lds16(const char* g, char* l) {
    __builtin_amdgcn_global_load_lds(
        (const __attribute__((address_space(1))) unsigned int*)g,
        (__attribute__((address_space(3))) unsigned int*)l,
        16, 0, 0);
}

// ======================= i8 MFMA PATH =======================

// x [B][D] f32 -> xi [B][D] i8 (+1/-1). float4 in, packed u32 out. Coalesced.
__global__ void pack_x_i8(const float* __restrict__ x, char* __restrict__ xi) {
    int idx = blockIdx.x * 256 + threadIdx.x;
    float4 v = ((const float4*)x)[idx];
    unsigned b0 = (v.x >= 0.f) ? 0x01u : 0xFFu;
    unsigned b1 = (v.y >= 0.f) ? 0x01u : 0xFFu;
    unsigned b2 = (v.z >= 0.f) ? 0x01u : 0xFFu;
    unsigned b3 = (v.w >= 0.f) ? 0x01u : 0xFFu;
    ((unsigned*)xi)[idx] = b0 | (b1 << 8) | (b2 << 16) | (b3 << 24);
}

// k [D][U] f32 -> kt [U][D] i8 (+1/-1), transposed via LDS 64x64 tile.
__global__ void pack_kt_i8(const float* __restrict__ k, char* __restrict__ kt) {
    __shared__ float tile[64][65];
    const int j0 = (blockIdx.x & 31) * 64;   // U tile
    const int d0 = (blockIdx.x >> 5) * 64;   // D tile
    const int tid = threadIdx.x;
    const int lane = tid & 63;
    const int wv = tid >> 6;
    for (int i = 0; i < 16; i++) {
        int row = i * 4 + wv;
        tile[row][lane] = k[(size_t)(d0 + row) * U_DIM + j0 + lane];
    }
    __syncthreads();
    const int u = tid >> 2;          // 0..63 output row (unit)
    const int g = tid & 3;           // 16-byte group along D
    union { char c[16]; int4 v; } pk;
#pragma unroll
    for (int j = 0; j < 16; j++)
        pk.c[j] = (tile[g * 16 + j][u] >= 0.f) ? (char)1 : (char)-1;
    *(int4*)(kt + (size_t)(j0 + u) * D_DIM + d0 + g * 16) = pk.v;
}

// out[i][j] = sum_k xi[i][k]*kt[j][k] + bias[j], exact in i32.
// 128x128 tile, 256 thr = 4 waves, wave = 64x64 (2x2 of mfma_i32_32x32x32_i8).
// DOUBLE-BUFFERED async staging: chunk ch+1's global_load_lds DMA is issued
// right after the barrier that consumes chunk ch -> a full compute phase
// (~800 cyc) hides the L2 latency; the vmcnt(0) drain at each barrier waits
// on already-landed loads. One barrier per chunk.
// Bank swizzle folded into the GLOBAL source (slot (r,g) <- group g^(r&7)).
__launch_bounds__(256)
__global__ void gemm_i8(const char* __restrict__ xi,   // [8192][2048]
                        const char* __restrict__ kt,   // [2048][2048]
                        const float* __restrict__ bias,
                        float* __restrict__ out) {
    __shared__ uint4 asmX[2][1024];  // A chunks: 2 x 16KB
    __shared__ uint4 bsmX[2][1024];  // B chunks: 2 x 16KB

    const int tid  = threadIdx.x;
    const int lane = tid & 63;
    const int w    = tid >> 6;       // 4 waves
    const int rows0 = blockIdx.y * 128;
    const int cols0 = blockIdx.x * 128;
    const int wr = (w >> 1) * 64;    // wave row offset
    const int wc = (w & 1) * 64;     // wave col offset
    const int m    = lane & 31;
    const int half = lane >> 5;

    v16i acc[2][2];
#pragma unroll
    for (int rt = 0; rt < 2; rt++)
#pragma unroll
        for (int ct = 0; ct < 2; ct++)
#pragma unroll
            for (int i = 0; i < 16; i++) acc[rt][ct][i] = 0;

    const char* abase = xi + (size_t)rows0 * D_DIM;
    const char* bbase = kt + (size_t)cols0 * D_DIM;

    // Stage chunk ch into buffer buf. Wave w covers slots [w*256, w*256+256).
    // slot -> (r = slot>>3, g = slot&7); global group gg = g ^ (r&7).
    auto stage = [&](int ch, int buf) {
#pragma unroll
        for (int i = 0; i < 4; i++) {
            const int slotbase = w * 256 + i * 64;
            const int slot = slotbase + lane;
            const int r  = slot >> 3;
            const int gg = (slot & 7) ^ (r & 7);
            const size_t goff = (size_t)r * D_DIM + ch * 128 + gg * 16;
            load_lds16(abase + goff, (char*)&asmX[buf][slotbase]);
            load_lds16(bbase + goff, (char*)&bsmX[buf][slotbase]);
        }
    };

    stage(0, 0);                     // prologue

    for (int ch = 0; ch < 16; ch++) {
        __syncthreads();             // staging of ch landed; buf (ch+1)&1 free
        if (ch < 15) stage(ch + 1, (ch + 1) & 1);

        const char* asmem = (const char*)asmX[ch & 1];
        const char* bsmem = (const char*)bsmX[ch & 1];
#pragma unroll
        for (int kk = 0; kk < 4; kk++) {
            const int col = ((kk * 2 + half) ^ (m & 7)) << 4;
            v4i a0 = *(const v4i*)(asmem + (wr + m)      * 128 + col);
            v4i a1 = *(const v4i*)(asmem + (wr + 32 + m) * 128 + col);
            v4i b0 = *(const v4i*)(bsmem + (wc + m)      * 128 + col);
            v4i b1 = *(const v4i*)(bsmem + (wc + 32 + m) * 128 + col);
            acc[0][0] = __builtin_amdgcn_mfma_i32_32x32x32_i8(a0, b0, acc[0][0], 0, 0, 0);
            acc[0][1] = __builtin_amdgcn_mfma_i32_32x32x32_i8(a0, b1, acc[0][1], 0, 0, 0);
            acc[1][0] = __builtin_amdgcn_mfma_i32_32x32x32_i8(a1, b0, acc[1][0], 0, 0, 0);
            acc[1][1] = __builtin_amdgcn_mfma_i32_32x32x32_i8(a1, b1, acc[1][1], 0, 0, 0);
        }
    }

    // C/D 32x32 layout (HW-verified R6): col = lane&31, row = (reg&3)+8*(reg>>2)+4*half
#pragma unroll
    for (int rt = 0; rt < 2; rt++)
#pragma unroll
        for (int ct = 0; ct < 2; ct++) {
            const int n = cols0 + wc + ct * 32 + m;
            const float bb = bias[n];
#pragma unroll
            for (int reg = 0; reg < 16; reg++) {
                const int row = (reg & 3) + 8 * (reg >> 2) + 4 * half;
                const size_t grow = (size_t)(rows0 + wr + rt * 32 + row);
                out[grow * U_DIM + n] = (float)acc[rt][ct][reg] + bb;
            }
        }
}

// ======================= BIT-PATH FALLBACK (R5, proven) =======================

__global__ void pack_x_kernel(const float* __restrict__ x,
                              unsigned long long* __restrict__ xb) {
    const int gwave = (blockIdx.x * blockDim.x + threadIdx.x) >> 6;
    const int lane  = threadIdx.x & 63;
    const size_t base = (size_t)gwave * 256;
    float v0 = x[base + lane];
    float v1 = x[base + 64 + lane];
    float v2 = x[base + 128 + lane];
    float v3 = x[base + 192 + lane];
    unsigned long long m0 = __ballot(v0 >= 0.0f);
    unsigned long long m1 = __ballot(v1 >= 0.0f);
    unsigned long long m2 = __ballot(v2 >= 0.0f);
    unsigned long long m3 = __ballot(v3 >= 0.0f);
    if (lane == 0) {
        ulonglong2* p = (ulonglong2*)(xb + (base >> 6));
        ulonglong2 a; a.x = m0; a.y = m1;
        ulonglong2 b; b.x = m2; b.y = m3;
        p[0] = a;
        p[1] = b;
    }
}

__global__ void pack_k_kernel(const float* __restrict__ k,
                              unsigned long long* __restrict__ kb) {
    __shared__ float tile[64][65];
    const int j0 = (blockIdx.x & 31) * 64;
    const int d0 = (blockIdx.x >> 5) * 64;
    const int tid  = threadIdx.x;
    const int lane = tid & 63;
    const int wv   = tid >> 6;
    for (int i = 0; i < 16; i++) {
        int row = i * 4 + wv;
        tile[row][lane] = k[(size_t)(d0 + row) * U_DIM + j0 + lane];
    }
    __syncthreads();
    for (int c = wv * 16; c < wv * 16 + 16; c++) {
        float v = tile[lane][c];
        unsigned long long m = __ballot(v >= 0.0f);
        if (lane == 0) kb[(size_t)(j0 + c) * (D_DIM / 64) + (d0 >> 6)] = m;
    }
}

__launch_bounds__(512)
__global__ void bgemm_kernel(const unsigned int* __restrict__ xb,
                             const unsigned int* __restrict__ kb,
                             const float* __restrict__ bias,
                             float* __restrict__ out) {
    __shared__ unsigned int xs[128 * KWORDS];
    __shared__ unsigned int ks[128 * KWORDS];
    const int bx  = blockIdx.x;
    const int by  = blockIdx.y;
    const int tid = threadIdx.x;
    const uint4* xsrc = (const uint4*)(xb + (size_t)(by * 128) * KWORDS);
    const uint4* ksrc = (const uint4*)(kb + (size_t)(bx * 128) * KWORDS);
#pragma unroll
    for (int i = 0; i < 4; i++) {
        int flat = tid + i * 512;
        int r    = flat >> 4;
        int g    = flat & 15;
        int sg   = g ^ ((r >> 3) & 7);
        uint4 xv = xsrc[flat];
        uint4 kv = ksrc[flat];
        *((uint4*)&xs[r * KWORDS + sg * 4]) = xv;
        *((uint4*)&ks[r * KWORDS + sg * 4]) = kv;
    }
    __syncthreads();
    const int tr   = (tid >> 4) * 4;
    const int tc   = (tid & 15) * 8;
    const int xswz = ((tid >> 4) >> 1) & 7;
    const int ksw  = tid & 7;
    int acc[4][8] = {};
    for (int w4 = 0; w4 < 16; w4++) {
        const int xcol = (w4 ^ xswz) * 4;
        const int kcol = (w4 ^ ksw) * 4;
        uint4 xv[4], kv[8];
#pragma unroll
        for (int r = 0; r < 4; r++) xv[r] = *((const uint4*)&xs[(tr + r) * KWORDS + xcol]);
#pragma unroll
        for (int c = 0; c < 8; c++) kv[c] = *((const uint4*)&ks[(tc + c) * KWORDS + kcol]);
#pragma unroll
        for (int r = 0; r < 4; r++)
#pragma unroll
            for (int c = 0; c < 8; c++) {
                acc[r][c] += __popc(xv[r].x ^ kv[c].x);
                acc[r][c] += __popc(xv[r].y ^ kv[c].y);
                acc[r][c] += __popc(xv[r].z ^ kv[c].z);
                acc[r][c] += __popc(xv[r].w ^ kv[c].w);
            }
    }
    const int row0 = by * 128 + tr;
    const int col0 = bx * 128 + tc;
    const float4 b0 = *((const float4*)&bias[col0]);
    const float4 b1 = *((const float4*)&bias[col0 + 4]);
#pragma unroll
    for (int r = 0; r < 4; r++) {
        float4 o0, o1;
        o0.x = (float)(D_DIM - 2 * acc[r][0]) + b0.x;
        o0.y = (float)(D_DIM - 2 * acc[r][1]) + b0.y;
        o0.z = (float)(D_DIM - 2 * acc[r][2]) + b0.z;
        o0.w = (float)(D_DIM - 2 * acc[r][3]) + b0.w;
        o1.x = (float)(D_DIM - 2 * acc[r][4]) + b1.x;
        o1.y = (float)(D_DIM - 2 * acc[r][5]) + b1.y;
        o1.z = (float)(D_DIM - 2 * acc[r][6]) + b1.z;
        o1.w = (float)(D_DIM - 2 * acc[r][7]) + b1.w;
        float* orow = &out[(size_t)(row0 + r) * U_DIM + col0];
        *((float4*)orow)       = o0;
        *((float4*)(orow + 4)) = o1;
    }
}

// ======================= launcher =======================

extern "C" void kernel_launch(void* const* d_in, const int* in_sizes, int n_in,
                              void* d_out, int out_size, void* d_ws, size_t ws_size,
                              hipStream_t stream) {
    const float* x    = (const float*)d_in[0];   // [8192][2048]
    const float* k    = (const float*)d_in[1];   // [2048][2048]
    const float* bias = (const float*)d_in[2];   // [2048]
    float* out = (float*)d_out;

    const size_t need_i8 = (size_t)B_DIM * D_DIM + (size_t)U_DIM * D_DIM; // ~21 MB
    if (ws_size >= need_i8) {
        char* xi = (char*)d_ws;                          // 16 MB
        char* kt = xi + (size_t)B_DIM * D_DIM;           // 4 MB
        pack_x_i8<<<(B_DIM * D_DIM) / 1024, 256, 0, stream>>>(x, xi);
        pack_kt_i8<<<32 * 32, 256, 0, stream>>>(k, kt);
        dim3 grid(U_DIM / 128, B_DIM / 128);
        gemm_i8<<<grid, 256, 0, stream>>>(xi, kt, bias, out);
    } else {
        unsigned long long* xbits = (unsigned long long*)d_ws;
        unsigned long long* kbits = (unsigned long long*)((char*)d_ws + (size_t)B_DIM * (D_DIM / 8));
        pack_x_kernel<<<(B_DIM * D_DIM) / 1024, 256, 0, stream>>>(x, xbits);
        pack_k_kernel<<<32 * 32, 256, 0, stream>>>(k, kbits);
        dim3 grid(U_DIM / 128, B_DIM / 128);
        bgemm_kernel<<<grid, 512, 0, stream>>>((const unsigned int*)xbits,
                                               (const unsigned int*)kbits, bias, out);
    }
}